// Round 1
// baseline (94.412 us; speedup 1.0000x reference)
//
#include <hip/hip_runtime.h>
#include <stdint.h>

#define NFEAT 16
#define NCOLS 969   // 1 bias + 16 deg1 + 136 deg2 + 816 deg3

// ---------------------------------------------------------------------------
// Kernel 1: build the column -> (i,j,k) combo table (packed bytes, 0xFF=unused)
// Ordering must match sklearn/jax reference:
//   col 0                : bias
//   cols 1..16           : x[i]
//   cols 17..152         : for i in 0..15: for j in i..15: x[i]*x[j]
//   cols 153..968        : for i: for j>=i: for k>=j: x[i]*x[j]*x[k]
// ---------------------------------------------------------------------------
__global__ void poly_build_table(uint32_t* __restrict__ tbl) {
    for (int col = threadIdx.x; col < NCOLS; col += blockDim.x) {
        uint32_t i = 0xFF, j = 0xFF, k = 0xFF;
        if (col == 0) {
            // bias: all 0xFF
        } else if (col <= NFEAT) {
            i = col - 1;
        } else if (col <= NFEAT + (NFEAT * (NFEAT + 1)) / 2) {
            int c = col - (NFEAT + 1);
            int ii = 0;
            while (c >= NFEAT - ii) { c -= NFEAT - ii; ++ii; }
            i = ii;
            j = ii + c;
        } else {
            int c = col - (NFEAT + 1 + (NFEAT * (NFEAT + 1)) / 2);
            int ii = 0;
            // count of (j,k) with ii<=j<=k<16 is (16-ii)*(17-ii)/2
            while (c >= ((NFEAT - ii) * (NFEAT + 1 - ii)) / 2) {
                c -= ((NFEAT - ii) * (NFEAT + 1 - ii)) / 2;
                ++ii;
            }
            int jj = ii;
            while (c >= NFEAT - jj) { c -= NFEAT - jj; ++jj; }
            i = ii;
            j = jj;
            k = jj + c;
        }
        tbl[col] = i | (j << 8) | (k << 16);
    }
}

// ---------------------------------------------------------------------------
// Kernel 2: flat grid-stride over all output elements; coalesced stores.
// ---------------------------------------------------------------------------
__global__ void __launch_bounds__(256)
poly_main(const float* __restrict__ x, float* __restrict__ out,
          const uint32_t* __restrict__ tbl, int total) {
    __shared__ uint32_t s_tbl[NCOLS];
    for (int t = threadIdx.x; t < NCOLS; t += blockDim.x) s_tbl[t] = tbl[t];
    __syncthreads();

    int idx = blockIdx.x * blockDim.x + threadIdx.x;
    int stride = gridDim.x * blockDim.x;
    for (int g = idx; g < total; g += stride) {
        int row = g / NCOLS;            // constant divisor -> magic multiply
        int col = g - row * NCOLS;
        uint32_t e = s_tbl[col];
        const float* xr = x + row * NFEAT;
        uint32_t i = e & 0xFFu;
        uint32_t j = (e >> 8) & 0xFFu;
        uint32_t k = (e >> 16) & 0xFFu;
        float v = 1.0f;
        if (i != 0xFFu) v = xr[i];
        if (j != 0xFFu) v *= xr[j];
        if (k != 0xFFu) v *= xr[k];
        out[g] = v;
    }
}

extern "C" void kernel_launch(void* const* d_in, const int* in_sizes, int n_in,
                              void* d_out, int out_size, void* d_ws, size_t ws_size,
                              hipStream_t stream) {
    const float* x = (const float*)d_in[0];
    float* out = (float*)d_out;
    uint32_t* tbl = (uint32_t*)d_ws;

    poly_build_table<<<1, 256, 0, stream>>>(tbl);

    int total = out_size;               // 65536 * 969
    int block = 256;
    int grid = (total + block - 1) / block;
    if (grid > 2048) grid = 2048;
    poly_main<<<grid, block, 0, stream>>>(x, out, tbl, total);
}

// Round 3
// 74.376 us; speedup vs baseline: 1.2694x; 1.2694x over previous
//
#include <hip/hip_runtime.h>
#include <stdint.h>

#define NFEAT 16
#define NCOLS 969   // 1 bias + 16 deg1 + 136 deg2 + 816 deg3

typedef float floatx4 __attribute__((ext_vector_type(4)));

// ---------------------------------------------------------------------------
// Kernel 1: build the column -> (i,j,k) combo table (packed bytes, 0xFF=unused)
// Ordering matches sklearn/jax PolynomialFeatures:
//   col 0                : bias
//   cols 1..16           : x[i]
//   cols 17..152         : for i: for j>=i: x[i]*x[j]
//   cols 153..968        : for i: for j>=i: for k>=j: x[i]*x[j]*x[k]
// ---------------------------------------------------------------------------
__global__ void poly_build_table(uint32_t* __restrict__ tbl) {
    for (int col = threadIdx.x; col < NCOLS; col += blockDim.x) {
        uint32_t i = 0xFF, j = 0xFF, k = 0xFF;
        if (col == 0) {
            // bias
        } else if (col <= NFEAT) {
            i = col - 1;
        } else if (col <= NFEAT + (NFEAT * (NFEAT + 1)) / 2) {
            int c = col - (NFEAT + 1);
            int ii = 0;
            while (c >= NFEAT - ii) { c -= NFEAT - ii; ++ii; }
            i = ii;
            j = ii + c;
        } else {
            int c = col - (NFEAT + 1 + (NFEAT * (NFEAT + 1)) / 2);
            int ii = 0;
            while (c >= ((NFEAT - ii) * (NFEAT + 1 - ii)) / 2) {
                c -= ((NFEAT - ii) * (NFEAT + 1 - ii)) / 2;
                ++ii;
            }
            int jj = ii;
            while (c >= NFEAT - jj) { c -= NFEAT - jj; ++jj; }
            i = ii;
            j = jj;
            k = jj + c;
        }
        tbl[col] = i | (j << 8) | (k << 16);
    }
}

// ---------------------------------------------------------------------------
// Kernel 2: 4 output elements per lane-iteration, float4 nontemporal stores.
// total4 = N_SAMPLES*NCOLS/4 (exact: 65536*969 % 4 == 0).
// ---------------------------------------------------------------------------
__global__ void __launch_bounds__(256)
poly_main4(const float* __restrict__ x, floatx4* __restrict__ out4,
           const uint32_t* __restrict__ tbl, int total4) {
    __shared__ uint32_t s_tbl[NCOLS];
    for (int t = threadIdx.x; t < NCOLS; t += blockDim.x) s_tbl[t] = tbl[t];
    __syncthreads();

    int idx = blockIdx.x * blockDim.x + threadIdx.x;
    int stride = gridDim.x * blockDim.x;
    for (int g4 = idx; g4 < total4; g4 += stride) {
        int g = g4 << 2;
        int row = g / NCOLS;            // compile-time-constant divisor -> magic mul
        int col = g - row * NCOLS;
        const float* xr = x + (row << 4);

        floatx4 pack;
        #pragma unroll
        for (int u = 0; u < 4; ++u) {
            uint32_t e = s_tbl[col];
            uint32_t i = e & 0xFFu;
            uint32_t j = (e >> 8) & 0xFFu;
            uint32_t k = (e >> 16) & 0xFFu;
            float p = 1.0f;
            if (i != 0xFFu) p = xr[i];
            if (j != 0xFFu) p *= xr[j];
            if (k != 0xFFu) p *= xr[k];
            pack[u] = p;
            if (++col == NCOLS) { col = 0; xr += NFEAT; }  // rare row carry
        }
        __builtin_nontemporal_store(pack, &out4[g4]);
    }
}

extern "C" void kernel_launch(void* const* d_in, const int* in_sizes, int n_in,
                              void* d_out, int out_size, void* d_ws, size_t ws_size,
                              hipStream_t stream) {
    const float* x = (const float*)d_in[0];
    floatx4* out4 = (floatx4*)d_out;
    uint32_t* tbl = (uint32_t*)d_ws;

    poly_build_table<<<1, 256, 0, stream>>>(tbl);

    int total4 = out_size >> 2;         // 65536*969/4 = 15,876,096
    int block = 256;
    int grid = (total4 + block - 1) / block;
    if (grid > 2048) grid = 2048;
    poly_main4<<<grid, block, 0, stream>>>(x, out4, tbl, total4);
}